// Round 4
// baseline (279.792 us; speedup 1.0000x reference)
//
#include <hip/hip_runtime.h>
#include <hip/hip_bf16.h>
#include <math.h>

// DistMult edge scoring: out[e] = sigmoid(sum_d h[u[e],d] * rel[etype[e],d] * h[v[e],d])
// N_NODES=100000, E=250000, D=384, N_ETYPES=8.
// Inputs: h (fp32), u (int32), v (int32), etype (int32), rel_weight (fp32). Out: fp32 [E].
//
// R3: bf16 shadow copy (R2) halved gather bytes but also halved per-lane load
// depth (9 uint4) -> main pass fell to ~4.7 TB/s delivered (latency wall).
// Fix: 8 lanes/edge -> 6 uint4 per operand per lane = 18 outstanding 16B
// loads (the depth that saturated 6.3 TB/s in R1). 128B contiguous segments
// per 8-lane group stay fully coalesced.

#define D 384
#define N_NODES_ELEMS (100000 * 384)          // h element count
#define H_BF16_BYTES  (100000 * 384 * 2)      // 76,800,000 bytes (16B aligned)

// ---- pass 1: fp32 -> packed bf16, 8 floats / thread ----
__global__ __launch_bounds__(256) void conv_kernel(
    const float* __restrict__ src, uint32_t* __restrict__ dst, int n8)
{
    int i = blockIdx.x * blockDim.x + threadIdx.x;
    if (i >= n8) return;
    const float4* s = (const float4*)(src) + (size_t)i * 2;
    float4 f0 = s[0];
    float4 f1 = s[1];
    uint4 o;
    o.x = (uint32_t)__bfloat16_as_ushort(__float2bfloat16(f0.x)) |
          ((uint32_t)__bfloat16_as_ushort(__float2bfloat16(f0.y)) << 16);
    o.y = (uint32_t)__bfloat16_as_ushort(__float2bfloat16(f0.z)) |
          ((uint32_t)__bfloat16_as_ushort(__float2bfloat16(f0.w)) << 16);
    o.z = (uint32_t)__bfloat16_as_ushort(__float2bfloat16(f1.x)) |
          ((uint32_t)__bfloat16_as_ushort(__float2bfloat16(f1.y)) << 16);
    o.w = (uint32_t)__bfloat16_as_ushort(__float2bfloat16(f1.z)) |
          ((uint32_t)__bfloat16_as_ushort(__float2bfloat16(f1.w)) << 16);
    ((uint4*)dst)[i] = o;
}

// ---- pass 2: gather bf16 rows, 8 lanes/edge, 6 uint4 per operand per lane ----
__global__ __launch_bounds__(256) void distmult_kernel(
    const uint32_t* __restrict__ hb,   // bf16-packed h [N_NODES][192 uints]
    const uint32_t* __restrict__ rb,   // bf16-packed rel [8][192]
    const int* __restrict__ u,
    const int* __restrict__ v,
    const int* __restrict__ etype,
    float* __restrict__ out,
    int n_edges)
{
    int tid  = blockIdx.x * blockDim.x + threadIdx.x;
    int e    = tid >> 3;            // 8 lanes per edge
    int lane = threadIdx.x & 7;
    if (e >= n_edges) return;

    const uint4* hu = (const uint4*)(hb + (size_t)u[e]     * (D / 2));
    const uint4* hv = (const uint4*)(hb + (size_t)v[e]     * (D / 2));
    const uint4* r  = (const uint4*)(rb + (size_t)etype[e] * (D / 2));

    // 48 uint4 per row / 8 lanes = 6 per operand per lane; issue all 18 first.
    uint4 a[6], b[6], c[6];
#pragma unroll
    for (int k = 0; k < 6; ++k) {
        int j = lane + k * 8;
        a[k] = hu[j];
        b[k] = hv[j];
        c[k] = r[j];
    }

    float s = 0.0f;
#pragma unroll
    for (int k = 0; k < 6; ++k) {
        const uint32_t* pa = &a[k].x;
        const uint32_t* pb = &b[k].x;
        const uint32_t* pc = &c[k].x;
#pragma unroll
        for (int q = 0; q < 4; ++q) {
            float alo = __uint_as_float(pa[q] << 16);
            float ahi = __uint_as_float(pa[q] & 0xffff0000u);
            float blo = __uint_as_float(pb[q] << 16);
            float bhi = __uint_as_float(pb[q] & 0xffff0000u);
            float clo = __uint_as_float(pc[q] << 16);
            float chi = __uint_as_float(pc[q] & 0xffff0000u);
            s += alo * clo * blo;
            s += ahi * chi * bhi;
        }
    }

    // Reduce across the 8-lane group.
#pragma unroll
    for (int off = 4; off >= 1; off >>= 1)
        s += __shfl_xor(s, off);

    if (lane == 0)
        out[e] = 1.0f / (1.0f + __expf(-s));
}

extern "C" void kernel_launch(void* const* d_in, const int* in_sizes, int n_in,
                              void* d_out, int out_size, void* d_ws, size_t ws_size,
                              hipStream_t stream) {
    const float* h     = (const float*)d_in[0];
    const int*   u     = (const int*)  d_in[1];
    const int*   v     = (const int*)  d_in[2];
    const int*   etype = (const int*)  d_in[3];
    const float* rel   = (const float*)d_in[4];
    float* out = (float*)d_out;

    int n_edges = in_sizes[1];          // E = 250000
    int n_rel   = in_sizes[4];          // 8*384 = 3072

    uint32_t* hb = (uint32_t*)d_ws;                          // 76.8 MB bf16 h
    uint32_t* rb = (uint32_t*)((char*)d_ws + H_BF16_BYTES);  // 6 KB bf16 rel

    int n8_h = N_NODES_ELEMS / 8;       // 4,800,000 threads
    conv_kernel<<<(n8_h + 255) / 256, 256, 0, stream>>>(h, hb, n8_h);
    int n8_r = n_rel / 8;               // 384 threads
    conv_kernel<<<(n8_r + 255) / 256, 256, 0, stream>>>(rel, rb, n8_r);

    long long threads_total = (long long)n_edges * 8;
    int grid = (int)((threads_total + 255) / 256);
    distmult_kernel<<<grid, 256, 0, stream>>>(hb, rb, u, v, etype, out, n_edges);
}